// Round 2
// 507.726 us; speedup vs baseline: 1.0489x; 1.0489x over previous
//
#include <hip/hip_runtime.h>

typedef __attribute__((ext_vector_type(8))) short short8;
typedef __attribute__((ext_vector_type(4))) float f32x4;
typedef __attribute__((ext_vector_type(4))) unsigned short ushx4;
typedef __attribute__((ext_vector_type(8))) unsigned short ushx8;

#define E_EDGES 800000
#define TILE 64
#define NTILES (E_EDGES / TILE)   // 12500 exact

// ws layout, ushort units (tables)
#define WS_TSRC 0
#define WS_TDST 12288
#define WS_TSTEP 24576
#define WS_TEQ 27136
#define WS_W2T 27392      // [n=0..127][k=0..127], W2T[n][k] = W[256+k][n]
#define WS_WRBFT 43776    // [n=0..127][k=0..31],  zero-padded past k=6
// byte offsets for per-edge prestage (tables end at 95744 B)
#define WSB_META 131072u                    // int4[E] = 12.8 MB
#define WSB_RBF8 (WSB_META + 16u*E_EDGES)   // ushx8[E] = 12.8 MB

__device__ __forceinline__ unsigned short f2bf(float f) {
    unsigned int u = __float_as_uint(f);
    u += 0x7fffu + ((u >> 16) & 1u);   // RNE
    return (unsigned short)(u >> 16);
}
__device__ __forceinline__ float bf2f(unsigned short u) {
    return __uint_as_float(((unsigned int)u) << 16);
}
__device__ __forceinline__ float silu_f(float v) {
    return v * __builtin_amdgcn_rcpf(1.0f + __expf(-v));
}

// ---------------- Kernel P: fold small-vocab gathers through W into tables ----
__global__ void precompute_kernel(const float* __restrict__ emb,
                                  const float* __restrict__ stept,
                                  const float* __restrict__ eqt,
                                  const float* __restrict__ Wrbf,
                                  const float* __restrict__ W,
                                  const float* __restrict__ bias,
                                  unsigned short* __restrict__ ws) {
    const int b = blockIdx.x;
    const int j = threadIdx.x;   // 128 threads
    if (b < 214) {
        const float* tab; int woff; unsigned short* outp; float acc = 0.f;
        if (b < 96)       { tab = emb   + b*128;        woff = 0;   outp = ws + WS_TSRC  + b*128; }
        else if (b < 192) { tab = emb   + (b-96)*128;   woff = 128; outp = ws + WS_TDST  + (b-96)*128; }
        else if (b < 212) { tab = stept + (b-192)*128;  woff = 384; outp = ws + WS_TSTEP + (b-192)*128; }
        else              { tab = eqt   + (b-212)*128;  woff = 512; outp = ws + WS_TEQ   + (b-212)*128; acc = bias[j]; }
        #pragma unroll 4
        for (int k = 0; k < 128; ++k)
            acc += tab[k] * W[(woff + k)*128 + j];
        outp[j] = f2bf(acc);
    } else {
        const int n = b - 214;   // 0..127
        ws[WS_W2T + n*128 + j] = f2bf(W[(256 + j)*128 + n]);
        if (j < 32)
            ws[WS_WRBFT + n*32 + j] = (j < 6) ? f2bf(Wrbf[j*128 + n]) : (unsigned short)0;
    }
}

// ---------------- Kernel I: per-edge prestage (meta, rbf->bf16, rbf_env) ------
__global__ __launch_bounds__(256)
void index_kernel(const int* __restrict__ Z, const int* __restrict__ stepv,
                  const int* __restrict__ src, const int* __restrict__ dst,
                  const int* __restrict__ equiv, const float* __restrict__ rbf,
                  const float* __restrict__ dvec,
                  unsigned char* __restrict__ wsb, float* __restrict__ out) {
    __shared__ float rl[1536];
    __shared__ float el[1536];
    const int t = threadIdx.x;
    const int B0 = blockIdx.x * 256;
    const int e = B0 + t;
    // coalesced rbf stage
    #pragma unroll
    for (int i = 0; i < 6; ++i) rl[t + i*256] = rbf[B0*6 + t + i*256];
    const int s  = src[e];
    const int dd = dst[e];
    const int qe = equiv[e];
    const float x = dvec[e] * 0.2f;
    int4* meta = (int4*)(wsb + WSB_META);
    meta[e] = make_int4(Z[s]*128, Z[dd]*128, stepv[s]*128, qe*128);
    // envelope * bessel into LDS (coalesced write-out later)
    const float inv = __builtin_amdgcn_rcpf(x);
    const float x2 = x*x;
    const float x5 = x2*x2*x;
    const float env = inv + x5*(-28.f + x*(48.f - 21.f*x));
    #pragma unroll
    for (int rr = 0; rr < 6; ++rr)
        el[t*6 + rr] = env * __sinf(x * (3.14159265358979f * (rr + 1))) * inv;
    __syncthreads();
    // rbf -> bf16 x8 (K-padded)
    ushx8 v;
    #pragma unroll
    for (int k = 0; k < 6; ++k) v[k] = f2bf(rl[t*6 + k]);
    v[6] = 0; v[7] = 0;
    ((ushx8*)(wsb + WSB_RBF8))[e] = v;
    #pragma unroll
    for (int i = 0; i < 6; ++i)
        __builtin_nontemporal_store(el[t + i*256],
            &out[(long)E_EDGES*128 + B0*6 + t + i*256]);
}

// ---------------- Kernel M: persistent fused edge kernel ----------------------
__global__ __launch_bounds__(256, 3)
void edge_kernel(const unsigned short* __restrict__ ws,
                 const unsigned char* __restrict__ wsb,
                 const float* __restrict__ brbf_g, float* __restrict__ out) {
    __shared__ alignas(16) unsigned short rbf_a[TILE*136];  // 17.4 KB, A-layout bf16
    __shared__ alignas(16) float sumbuf[TILE*132];          // 33.8 KB, table sums f32

    const int t = threadIdx.x;
    const int lane = t & 63;
    const int w = t >> 6;
    const int q = lane >> 4;
    const int r = lane & 15;
    const int mh = w >> 1;        // edge sub-tile [mh*16, +16)
    const int nh = w & 1;         // col half [nh*64, +64)
    const int arow = mh*16 + r;

    const unsigned short* W2T = ws + WS_W2T;
    const unsigned short* WRB = ws + WS_WRBFT;
    const int4* g_meta = (const int4*)(wsb + WSB_META);
    const ushx8* g_rbf8 = (const ushx8*)(wsb + WSB_RBF8);

    // block-invariant B-fragments in VGPRs
    short8 w2f[16];
    short8 wrbf[4];
    float  brbf[4];
    #pragma unroll
    for (int nt = 0; nt < 4; ++nt) {
        const int n = nh*64 + nt*16 + r;
        #pragma unroll
        for (int ks = 0; ks < 4; ++ks)
            w2f[nt*4+ks] = *(const short8*)(W2T + n*128 + ks*32 + q*8);
        wrbf[nt] = *(const short8*)(WRB + n*32 + q*8);
        brbf[nt] = brbf_g[n];
    }

    // phase-1a coalesced-gather coordinates: 16 lanes cover one 256 B table row
    const int el8 = t >> 4;          // edge sub-index 0..15
    const int c0  = (t & 15) * 8;    // col chunk (8 ushorts = 16 B)

    for (int tile = blockIdx.x; tile < NTILES; tile += gridDim.x) {
        const int base = tile * TILE;

        // ---- phase 1a: table-sum prestage, coalesced row reads ----
        // each iteration: 16 edges x 128 cols; 16-lane groups read whole rows
        #pragma unroll
        for (int i = 0; i < 4; ++i) {
            const int e = i*16 + el8;
            const int4 mo = g_meta[base + e];          // broadcast across 16 lanes
            ushx8 u0 = *(const ushx8*)(ws + WS_TSRC  + mo.x + c0);
            ushx8 u1 = *(const ushx8*)(ws + WS_TDST  + mo.y + c0);
            ushx8 u2 = *(const ushx8*)(ws + WS_TSTEP + mo.z + c0);
            ushx8 u3 = *(const ushx8*)(ws + WS_TEQ   + mo.w + c0);
            float* srow = sumbuf + e*132 + c0;
            f32x4 sv0, sv1;
            #pragma unroll
            for (int k = 0; k < 4; ++k) {
                sv0[k] = bf2f(u0[k])   + bf2f(u1[k])   + bf2f(u2[k])   + bf2f(u3[k]);
                sv1[k] = bf2f(u0[k+4]) + bf2f(u1[k+4]) + bf2f(u2[k+4]) + bf2f(u3[k+4]);
            }
            *(f32x4*)(srow)     = sv0;
            *(f32x4*)(srow + 4) = sv1;
        }

        // ---- phase 1b: mini-MFMA rbf_a = silu(rbf @ W_rbf + b), A-frag direct from global
        {
            short8 a0 = (short8)0;
            if (q == 0) a0 = *(const short8*)(g_rbf8 + base + arow);
            #pragma unroll
            for (int nt = 0; nt < 4; ++nt) {
                const float bb = brbf[nt];
                f32x4 c = {bb, bb, bb, bb};
                c = __builtin_amdgcn_mfma_f32_16x16x32_bf16(a0, wrbf[nt], c, 0, 0, 0);
                const int col = nh*64 + nt*16 + r;
                #pragma unroll
                for (int reg = 0; reg < 4; ++reg)
                    rbf_a[(mh*16 + q*4 + reg)*136 + col] = f2bf(silu_f(c[reg]));
            }
        }
        __syncthreads();

        // ---- phase 2: main MFMA (C init = table sums), silu, direct stores ----
        f32x4 acc[4];
        #pragma unroll
        for (int nt = 0; nt < 4; ++nt) {
            const int col = nh*64 + nt*16 + r;
            #pragma unroll
            for (int reg = 0; reg < 4; ++reg)
                acc[nt][reg] = sumbuf[(mh*16 + q*4 + reg)*132 + col];
        }
        #pragma unroll
        for (int ks = 0; ks < 4; ++ks) {
            short8 a = *(const short8*)(rbf_a + arow*136 + ks*32 + q*8);
            #pragma unroll
            for (int nt = 0; nt < 4; ++nt)
                acc[nt] = __builtin_amdgcn_mfma_f32_16x16x32_bf16(a, w2f[nt*4+ks], acc[nt], 0, 0, 0);
        }
        #pragma unroll
        for (int nt = 0; nt < 4; ++nt) {
            const int col = nh*64 + nt*16 + r;
            #pragma unroll
            for (int reg = 0; reg < 4; ++reg)
                __builtin_nontemporal_store(silu_f(acc[nt][reg]),
                    &out[(long)(base + mh*16 + q*4 + reg)*128 + col]);
        }
        __syncthreads();   // protect sumbuf/rbf_a for next tile
    }
}

extern "C" void kernel_launch(void* const* d_in, const int* in_sizes, int n_in,
                              void* d_out, int out_size, void* d_ws, size_t ws_size,
                              hipStream_t stream) {
    const int*   Z     = (const int*)d_in[0];
    const int*   stepv = (const int*)d_in[1];
    const int*   src   = (const int*)d_in[2];
    const int*   dst   = (const int*)d_in[3];
    const int*   equiv = (const int*)d_in[4];
    const float* rbf   = (const float*)d_in[5];
    const float* dvec  = (const float*)d_in[6];
    const float* emb   = (const float*)d_in[7];
    const float* stept = (const float*)d_in[8];
    const float* eqt   = (const float*)d_in[9];
    const float* Wrbf  = (const float*)d_in[10];
    const float* brbf  = (const float*)d_in[11];
    const float* W     = (const float*)d_in[12];
    const float* bias  = (const float*)d_in[13];
    unsigned short* ws = (unsigned short*)d_ws;
    unsigned char* wsb = (unsigned char*)d_ws;
    float* out = (float*)d_out;

    precompute_kernel<<<342, 128, 0, stream>>>(emb, stept, eqt, Wrbf, W, bias, ws);
    index_kernel<<<3125, 256, 0, stream>>>(Z, stepv, src, dst, equiv, rbf, dvec, wsb, out);
    edge_kernel<<<768, 256, 0, stream>>>(ws, wsb, brbf, out);
}